// Round 1
// baseline (480.081 us; speedup 1.0000x reference)
//
#include <hip/hip_runtime.h>

// SimpleCA: fused toroidal depthwise 3x3 stencil + 1x1 MLP (4->6 relu ->4) + masked residual.
// Layout NHWC, C=4 -> one float4 per pixel. Memory-bound: ideal ~603 MB @ ~6.3 TB/s ~ 96 us.

constexpr int H = 512, W = 512, C = 4, HIDN = 6, R = 8;

__device__ __forceinline__ float4 ld4(const float* p) {
    return *reinterpret_cast<const float4*>(p);
}

__global__ __launch_bounds__(256) void ca_kernel(
    const float* __restrict__ x,
    const float* __restrict__ rnd,
    const float* __restrict__ w1,
    const float* __restrict__ b1,
    const float* __restrict__ w2,
    float* __restrict__ out)
{
    const int t = blockIdx.x * blockDim.x + threadIdx.x;
    const int w     = t & (W - 1);          // lane-fast along W -> coalesced
    const int strip = t >> 9;               // / W
    const int h0    = (strip & (H / R - 1)) * R;
    const int b     = strip >> 6;           // / (H/R)

    const int wm = (w == 0) ? (W - 1) : (w - 1);
    const int wp = (w == W - 1) ? 0 : (w + 1);

    // Weights: uniform addresses -> s_load; tiny.
    float w1r[C * HIDN], b1r[HIDN], w2r[HIDN * C];
    #pragma unroll
    for (int i = 0; i < C * HIDN; ++i) w1r[i] = w1[i];
    #pragma unroll
    for (int i = 0; i < HIDN; ++i) b1r[i] = b1[i];
    #pragma unroll
    for (int i = 0; i < HIDN * C; ++i) w2r[i] = w2[i];

    const float* xb = x   + (size_t)b * H * W * C;
    const float* rb = rnd + (size_t)b * H * W;
    float*       ob = out + (size_t)b * H * W * C;

    // Rolling 3-row window: a = row h-1, c = row h, d = row h+1; cols {wm,w,wp}.
    float4 a0, a1, a2, c0, c1, c2, d0, d1, d2;
    {
        const int hm = (h0 == 0) ? (H - 1) : (h0 - 1);
        a0 = ld4(xb + ((hm * W + wm) << 2));
        a1 = ld4(xb + ((hm * W + w ) << 2));
        a2 = ld4(xb + ((hm * W + wp) << 2));
        c0 = ld4(xb + ((h0 * W + wm) << 2));
        c1 = ld4(xb + ((h0 * W + w ) << 2));
        c2 = ld4(xb + ((h0 * W + wp) << 2));
        const int h1 = h0 + 1;  // h0 <= H-R so h1 < H
        d0 = ld4(xb + ((h1 * W + wm) << 2));
        d1 = ld4(xb + ((h1 * W + w ) << 2));
        d2 = ld4(xb + ((h1 * W + wp) << 2));
    }

    #pragma unroll
    for (int r = 0; r < R; ++r) {
        const int h = h0 + r;

        // Depthwise stencils (cross-correlation, no flip — XLA conv semantics).
        const float p0 = c1.x;                                           // identity (ch 0)
        const float p1 = (a2.y - a0.y) + 2.f * (c2.y - c0.y)             // sobel_x (ch 1)
                       + (d2.y - d0.y);
        const float p2 = (d0.z - a0.z) + 2.f * (d1.z - a1.z)             // sobel_y (ch 2)
                       + (d2.z - a2.z);
        const float p3 = a0.w + 2.f * a1.w + a2.w                        // laplacian (ch 3)
                       + 2.f * c0.w - 12.f * c1.w + 2.f * c2.w
                       + d0.w + 2.f * d1.w + d2.w;

        float hid[HIDN];
        #pragma unroll
        for (int j = 0; j < HIDN; ++j) {
            float v = p0 * w1r[j] + p1 * w1r[HIDN + j] + p2 * w1r[2 * HIDN + j]
                    + p3 * w1r[3 * HIDN + j] + b1r[j];
            hid[j] = v > 0.f ? v : 0.f;
        }
        float dx0 = 0.f, dx1 = 0.f, dx2 = 0.f, dx3 = 0.f;
        #pragma unroll
        for (int j = 0; j < HIDN; ++j) {
            dx0 += hid[j] * w2r[j * 4 + 0];
            dx1 += hid[j] * w2r[j * 4 + 1];
            dx2 += hid[j] * w2r[j * 4 + 2];
            dx3 += hid[j] * w2r[j * 4 + 3];
        }

        const float mask = floorf(rb[h * W + w] + 0.5f);  // exact ref semantics
        float4 o;
        o.x = c1.x + dx0 * mask;
        o.y = c1.y + dx1 * mask;
        o.z = c1.z + dx2 * mask;
        o.w = c1.w + dx3 * mask;
        *reinterpret_cast<float4*>(ob + ((h * W + w) << 2)) = o;

        // Roll window down one row.
        a0 = c0; a1 = c1; a2 = c2;
        c0 = d0; c1 = d1; c2 = d2;
        if (r < R - 1) {
            int hn = h + 2;
            if (hn >= H) hn -= H;   // wraps only on the last strip of an image
            d0 = ld4(xb + ((hn * W + wm) << 2));
            d1 = ld4(xb + ((hn * W + w ) << 2));
            d2 = ld4(xb + ((hn * W + wp) << 2));
        }
    }
}

extern "C" void kernel_launch(void* const* d_in, const int* in_sizes, int n_in,
                              void* d_out, int out_size, void* d_ws, size_t ws_size,
                              hipStream_t stream) {
    const float* x   = (const float*)d_in[0];
    const float* rnd = (const float*)d_in[1];
    const float* w1  = (const float*)d_in[2];
    const float* b1  = (const float*)d_in[3];
    const float* w2  = (const float*)d_in[4];
    float* out = (float*)d_out;

    const int B = in_sizes[0] / (H * W * C);          // 64
    const int total_threads = B * (H / R) * W;        // 2,097,152
    dim3 grid(total_threads / 256), block(256);
    hipLaunchKernelGGL(ca_kernel, grid, block, 0, stream, x, rnd, w1, b1, w2, out);
}